// Round 20
// baseline (215.409 us; speedup 1.0000x reference)
//
#include <hip/hip_runtime.h>
#include <hip/hip_bf16.h>
#include <math.h>
#include <float.h>

// Problem constants
constexpr int CB = 16;        // batch
constexpr int CC = 256;       // channels
constexpr int PH = 96, PW = 96, PHW = 9216;
constexpr int MH = 48, MW = 48, MHW = 2304;
constexpr int GSTEPS = MHW / 32;   // 72 mfma k-steps
constexpr int TPAD = 100;     // padded tmp row stride

typedef __bf16 bf16x8 __attribute__((ext_vector_type(8)));
typedef float f32x4 __attribute__((ext_vector_type(4)));
typedef unsigned short ushort8 __attribute__((ext_vector_type(8)));

__device__ __forceinline__ float sigmoidf_(float x) { return 1.f / (1.f + __expf(-x)); }

__device__ __forceinline__ unsigned f2ord(float f) {
  unsigned u = __float_as_uint(f);
  return (u & 0x80000000u) ? ~u : (u | 0x80000000u);
}

// Truncation-based 3-term bf16 split: v = b1 + b2 + b3 + err, |err| <= 2^-24 |v|.
__device__ __forceinline__ void split3(float v, unsigned short& h1, unsigned short& h2,
                                       unsigned short& h3) {
  unsigned u1 = __float_as_uint(v) & 0xFFFF0000u;
  float r1 = v - __uint_as_float(u1);
  unsigned u2 = __float_as_uint(r1) & 0xFFFF0000u;
  float r2 = r1 - __uint_as_float(u2);
  h1 = (unsigned short)(u1 >> 16);
  h2 = (unsigned short)(u2 >> 16);
  h3 = (unsigned short)(__float_as_uint(r2) >> 16);
}

// ---------------- Kernel A+B merged: stats + bf16 planes for both inputs
// fp path: 1-deep software pipeline (prefetch next task's 4 rows while computing
// current) -> ~8 loads in flight/thread at unchanged compute order (bitwise identical).
__global__ __launch_bounds__(256) void k_stats(const float* __restrict__ fp,
                                               const float* __restrict__ fms,
                                               unsigned short* __restrict__ padjP,
                                               unsigned short* __restrict__ msP,
                                               float* __restrict__ meanp,
                                               float* __restrict__ pn,
                                               float* __restrict__ meanms,
                                               float* __restrict__ msn) {
  __shared__ __align__(16) float smem[MH * TPAD];   // 19.2 KB (aliased by both paths)
  __shared__ float rs[4], rss[4];
  const int tid = threadIdx.x;
  if (blockIdx.x < 4096) {
    // ---- f_p path ----
    const int bc = blockIdx.x;
    float (*tmp)[TPAD] = (float(*)[TPAD])smem;
    const float* img = fp + (size_t)bc * PHW;
    const int NT4 = MH * (PW / 4);   // 1152
    float s = 0.f, ss = 0.f;

    auto task_load = [&](int idx4, float4* r4) {
      const int u = idx4 / (PW / 4), w4 = (idx4 - u * (PW / 4)) * 4;
      int r0, r1, r2, r3;
      if (u == 0) { r0 = 0; r1 = 1; r2 = 2; r3 = 2; }
      else if (u == MH - 1) { r0 = PH - 3; r1 = PH - 2; r2 = PH - 1; r3 = PH - 1; }
      else { r0 = 2 * u - 1; r1 = 2 * u; r2 = 2 * u + 1; r3 = 2 * u + 2; }
      r4[0] = *(const float4*)&img[r0 * PW + w4];
      r4[1] = *(const float4*)&img[r1 * PW + w4];
      r4[2] = *(const float4*)&img[r2 * PW + w4];
      r4[3] = *(const float4*)&img[r3 * PW + w4];
    };
    auto task_compute = [&](int idx4, const float4* r4) {
      const int u = idx4 / (PW / 4), w4 = (idx4 - u * (PW / 4)) * 4;
      const float4 a = r4[0], b = r4[1], c = r4[2], d = r4[3];
      float4 v, p0, p1;
      if (u == 0) {
        v.x = a.x + 0.75f * b.x + 0.25f * c.x;
        v.y = a.y + 0.75f * b.y + 0.25f * c.y;
        v.z = a.z + 0.75f * b.z + 0.25f * c.z;
        v.w = a.w + 0.75f * b.w + 0.25f * c.w;
        p0 = a; p1 = b;
      } else if (u == MH - 1) {
        v.x = 0.25f * a.x + 0.75f * b.x + c.x;
        v.y = 0.25f * a.y + 0.75f * b.y + c.y;
        v.z = 0.25f * a.z + 0.75f * b.z + c.z;
        v.w = 0.25f * a.w + 0.75f * b.w + c.w;
        p0 = b; p1 = c;
      } else {
        v.x = 0.25f * (a.x + d.x) + 0.75f * (b.x + c.x);
        v.y = 0.25f * (a.y + d.y) + 0.75f * (b.y + c.y);
        v.z = 0.25f * (a.z + d.z) + 0.75f * (b.z + c.z);
        v.w = 0.25f * (a.w + d.w) + 0.75f * (b.w + c.w);
        p0 = b; p1 = c;
      }
      s += (p0.x + p0.y + p0.z + p0.w) + (p1.x + p1.y + p1.z + p1.w);
      ss += (p0.x * p0.x + p0.y * p0.y + p0.z * p0.z + p0.w * p0.w) +
            (p1.x * p1.x + p1.y * p1.y + p1.z * p1.z + p1.w * p1.w);
      *(float4*)&tmp[u][w4] = v;
    };

    float4 cur[4], nxt[4];
    task_load(tid, cur);                         // tid < 1152 always (256 <= 1152)
    for (int idx4 = tid; idx4 < NT4; idx4 += 256) {
      const int next = idx4 + 256;
      if (next < NT4) task_load(next, nxt);
      task_compute(idx4, cur);
#pragma unroll
      for (int t = 0; t < 4; ++t) cur[t] = nxt[t];
    }
    for (int off = 32; off; off >>= 1) { s += __shfl_down(s, off); ss += __shfl_down(ss, off); }
    if ((tid & 63) == 0) { rs[tid >> 6] = s; rss[tid >> 6] = ss; }
    __syncthreads();
    if (tid == 0) {
      float S = rs[0] + rs[1] + rs[2] + rs[3];
      float SS = rss[0] + rss[1] + rss[2] + rss[3];
      meanp[bc] = S / (float)PHW;
      pn[bc] = sqrtf(fmaxf(SS - S * S / (float)PHW, 0.f));
    }
    // Phase 3: col adjoint + split3, 8 outputs per task, ushort8 stores.
    unsigned short* outp = padjP + (size_t)bc * 3 * MHW;   // [c][plane][k]
    for (int idx = tid; idx < MH * 6; idx += 256) {        // 288 tasks
      const int u = idx / 6, q = idx - u * 6;
      const int v0 = 8 * q;
      const float* r = tmp[u];
      float val[8];
#pragma unroll
      for (int t = 0; t < 8; ++t) {
        const int v = v0 + t;
        if (v == 0)
          val[t] = r[0] + 0.75f * r[1] + 0.25f * r[2];
        else if (v == MW - 1)
          val[t] = 0.25f * r[PW - 3] + 0.75f * r[PW - 2] + r[PW - 1];
        else
          val[t] = 0.25f * (r[2 * v - 1] + r[2 * v + 2]) + 0.75f * (r[2 * v] + r[2 * v + 1]);
      }
      ushort8 h1, h2, h3;
#pragma unroll
      for (int t = 0; t < 8; ++t)
        split3(val[t], ((unsigned short*)&h1)[t], ((unsigned short*)&h2)[t],
               ((unsigned short*)&h3)[t]);
      const int k0 = u * MW + v0;
      *(ushort8*)&outp[k0] = h1;
      *(ushort8*)&outp[MHW + k0] = h2;
      *(ushort8*)&outp[2 * MHW + k0] = h3;
    }
  } else {
    // ---- f_ms path ----
    const int bc = blockIdx.x - 4096;
    float* m = smem;            // 2304 floats
    float* t = smem + MHW;      // 2304 floats (fits: 48*100 = 4800 >= 4608)
    const float* img = fms + (size_t)bc * MHW;
    float s = 0.f;
    for (int q = tid; q < MHW / 4; q += 256) {
      float4 v = ((const float4*)img)[q];
      ((float4*)m)[q] = v;
      s += v.x + v.y + v.z + v.w;
    }
    for (int off = 32; off; off >>= 1) s += __shfl_down(s, off);
    if ((tid & 63) == 0) rs[tid >> 6] = s;
    __syncthreads();
    const float mean = (rs[0] + rs[1] + rs[2] + rs[3]) / (float)MHW;
    for (int idx = tid; idx < MHW; idx += 256) {
      const int i = idx / MW, j = idx - i * MW;
      const float c = m[idx];
      const float l = (j > 0) ? m[idx - 1] : 0.f;
      const float r = (j < MW - 1) ? m[idx + 1] : 0.f;
      const float dj = (j == 0 || j == MW - 1) ? 1.625f : 1.25f;
      t[idx] = dj * c + 0.375f * (l + r);
    }
    __syncthreads();
    float ss = 0.f;
    for (int idx = tid; idx < MHW; idx += 256) {
      const int i = idx / MW;
      const float c = t[idx];
      const float up = (i > 0) ? t[idx - MW] : 0.f;
      const float dn = (i < MH - 1) ? t[idx + MW] : 0.f;
      const float di = (i == 0 || i == MH - 1) ? 1.625f : 1.25f;
      ss += m[idx] * (di * c + 0.375f * (up + dn));
    }
    for (int off = 32; off; off >>= 1) ss += __shfl_down(ss, off);
    if ((tid & 63) == 0) rss[tid >> 6] = ss;
    __syncthreads();
    if (tid == 0) {
      float SS = rss[0] + rss[1] + rss[2] + rss[3];
      meanms[bc] = mean;
      msn[bc] = sqrtf(fmaxf(SS - (float)PHW * mean * mean, 0.f));
    }
    unsigned short* outp = msP + (size_t)bc * 3 * MHW;   // [c][plane][k]
    for (int i8 = tid; i8 < MHW / 8; i8 += 256) {        // 288 tasks
      const int i = 8 * i8;
      float4 va = *(const float4*)&m[i];
      float4 vb = *(const float4*)&m[i + 4];
      ushort8 h1, h2, h3;
      split3(va.x, ((unsigned short*)&h1)[0], ((unsigned short*)&h2)[0], ((unsigned short*)&h3)[0]);
      split3(va.y, ((unsigned short*)&h1)[1], ((unsigned short*)&h2)[1], ((unsigned short*)&h3)[1]);
      split3(va.z, ((unsigned short*)&h1)[2], ((unsigned short*)&h2)[2], ((unsigned short*)&h3)[2]);
      split3(va.w, ((unsigned short*)&h1)[3], ((unsigned short*)&h2)[3], ((unsigned short*)&h3)[3]);
      split3(vb.x, ((unsigned short*)&h1)[4], ((unsigned short*)&h2)[4], ((unsigned short*)&h3)[4]);
      split3(vb.y, ((unsigned short*)&h1)[5], ((unsigned short*)&h2)[5], ((unsigned short*)&h3)[5]);
      split3(vb.z, ((unsigned short*)&h1)[6], ((unsigned short*)&h2)[6], ((unsigned short*)&h3)[6]);
      split3(vb.w, ((unsigned short*)&h1)[7], ((unsigned short*)&h2)[7], ((unsigned short*)&h3)[7]);
      *(ushort8*)&outp[i] = h1;
      *(ushort8*)&outp[MHW + i] = h2;
      *(ushort8*)&outp[2 * MHW + i] = h3;
    }
  }
}

// ---------------- Kernel C: split-bf16 MFMA GEMM, double-buffered (1 barrier/step) ----------------
__global__ __launch_bounds__(256) void k_gemm(const unsigned short* __restrict__ msP,
                                              const unsigned short* __restrict__ padjP,
                                              float* __restrict__ dotp) {
  __shared__ unsigned short As[2][2][3][64][40];   // [buf][mat][plane][row][k] = 122880 B
  const int n = blockIdx.x;                     // 0..255
  const int xcd = n & 7, slot = n >> 3;
  const int b = xcd * 2 + (slot >> 4);          // 2 batches per XCD
  const int xy = slot & 15;
  const int i0 = (xy >> 2) * 64, j0 = (xy & 3) * 64;
  const int tid = threadIdx.x, lane = tid & 63, wid = tid >> 6;
  const int wr = wid >> 1, wc = wid & 1;        // wave quadrant
  const int fr = lane & 15, fq = lane >> 4;

  const unsigned short* mats[2] = {
    msP + (size_t)(b * CC + i0) * 3 * MHW,
    padjP + (size_t)(b * CC + j0) * 3 * MHW
  };
  const unsigned short* gsrc[6];
  int lmat[6], lpl[6], lrow[6], lch[6];
#pragma unroll
  for (int q = 0; q < 6; ++q) {
    int t = tid + q * 256;                      // 1536 tasks: 128 rows x 3 planes x 4 chunks
    int ch = t & 3, pl = (t >> 2) % 3, r128 = t / 12;
    int mat = r128 >> 6, row = r128 & 63;
    gsrc[q] = mats[mat] + ((size_t)row * 3 + pl) * MHW + ch * 8;
    lmat[q] = mat; lpl[q] = pl; lrow[q] = row; lch[q] = ch;
  }
  bf16x8 stg[6];
  f32x4 acc[2][2] = {};

  auto g_load = [&](int kt) {
#pragma unroll
    for (int q = 0; q < 6; ++q) stg[q] = *(const bf16x8*)(gsrc[q] + kt);
  };
  auto l_store = [&](int buf) {
#pragma unroll
    for (int q = 0; q < 6; ++q)
      *(bf16x8*)&As[buf][lmat[q]][lpl[q]][lrow[q]][lch[q] * 8] = stg[q];
  };

  g_load(0);
  l_store(0);
  if (GSTEPS > 1) g_load(32);
  __syncthreads();
  int cur = 0;
  for (int step = 0; step < GSTEPS; ++step) {
    if (step + 1 < GSTEPS) l_store(cur ^ 1);     // store prefetched step+1 into idle buffer
    if (step + 2 < GSTEPS) g_load((step + 2) * 32);
    bf16x8 af[2][3], bfr[2][3];
#pragma unroll
    for (int ti = 0; ti < 2; ++ti)
#pragma unroll
      for (int p = 0; p < 3; ++p) {
        af[ti][p] = *(const bf16x8*)&As[cur][0][p][wr * 32 + ti * 16 + fr][fq * 8];
        bfr[ti][p] = *(const bf16x8*)&As[cur][1][p][wc * 32 + ti * 16 + fr][fq * 8];
      }
#pragma unroll
    for (int ti = 0; ti < 2; ++ti)
#pragma unroll
      for (int tj = 0; tj < 2; ++tj) {
        f32x4 c = acc[ti][tj];
        c = __builtin_amdgcn_mfma_f32_16x16x32_bf16(af[ti][0], bfr[tj][0], c, 0, 0, 0);
        c = __builtin_amdgcn_mfma_f32_16x16x32_bf16(af[ti][0], bfr[tj][1], c, 0, 0, 0);
        c = __builtin_amdgcn_mfma_f32_16x16x32_bf16(af[ti][1], bfr[tj][0], c, 0, 0, 0);
        c = __builtin_amdgcn_mfma_f32_16x16x32_bf16(af[ti][0], bfr[tj][2], c, 0, 0, 0);
        c = __builtin_amdgcn_mfma_f32_16x16x32_bf16(af[ti][1], bfr[tj][1], c, 0, 0, 0);
        c = __builtin_amdgcn_mfma_f32_16x16x32_bf16(af[ti][2], bfr[tj][0], c, 0, 0, 0);
        acc[ti][tj] = c;
      }
    __syncthreads();   // waves done reading As[cur]; stores to As[cur^1] visible
    cur ^= 1;
  }
  // Epilogue: C/D layout col = lane&15, row = (lane>>4)*4 + reg  [m89-verified]
  float* drow = dotp + ((size_t)b * CC + i0) * CC + j0;
#pragma unroll
  for (int ti = 0; ti < 2; ++ti)
#pragma unroll
    for (int tj = 0; tj < 2; ++tj)
#pragma unroll
      for (int j = 0; j < 4; ++j) {
        int row = wr * 32 + ti * 16 + fq * 4 + j;
        int col = wc * 32 + tj * 16 + fr;
        drow[(size_t)row * CC + col] = acc[ti][tj][j];
      }
}

// ---------------- Kernel D: merged rowmax + group select + bitonic sort (per batch) ----------------
__global__ __launch_bounds__(256) void k_select(const float* __restrict__ dotp,
                                                const float* __restrict__ meanp,
                                                const float* __restrict__ pn,
                                                const float* __restrict__ meanms,
                                                const float* __restrict__ msn,
                                                float* __restrict__ sscore,
                                                int* __restrict__ svals,
                                                int* __restrict__ cnt) {
  const int b = blockIdx.x, tid = threadIdx.x;
  __shared__ float mv[CC];
  __shared__ int sidx[CC];
  __shared__ float gsc[CC];
  __shared__ int pres[CC];
  __shared__ unsigned long long keys[CC];
  __shared__ float r1[4], r2[4];
  __shared__ int r3[4];
  __shared__ __align__(16) float mps[CC], pns[CC];
  mps[tid] = meanp[b * CC + tid];
  pns[tid] = pn[b * CC + tid];
  __syncthreads();
  const int r = b * CC + tid;
  const float* d0 = dotp + (size_t)r * CC;
  const float mm = meanms[r];
  const float inv = 100.f / msn[r];
  float best = -INFINITY; int bj = 0;
  for (int blk = 0; blk < 8; ++blk) {
    float4 v[8];
#pragma unroll
    for (int t = 0; t < 8; ++t) v[t] = ((const float4*)d0)[blk * 8 + t];
#pragma unroll
    for (int t = 0; t < 8; ++t) {
      const int j4 = blk * 8 + t;
      float4 mp4 = ((const float4*)mps)[j4];
      float4 pn4 = ((const float4*)pns)[j4];
      float sv[4];
      sv[0] = (v[t].x - (float)PHW * mm * mp4.x) * inv / pn4.x;
      sv[1] = (v[t].y - (float)PHW * mm * mp4.y) * inv / pn4.y;
      sv[2] = (v[t].z - (float)PHW * mm * mp4.z) * inv / pn4.z;
      sv[3] = (v[t].w - (float)PHW * mm * mp4.w) * inv / pn4.w;
#pragma unroll
      for (int q = 0; q < 4; ++q)
        if (sv[q] > best) { best = sv[q]; bj = j4 * 4 + q; }
    }
  }
  const float v = best;
  sidx[tid] = bj;
  // ---- group logic (verbatim) ----
  float m = v;
  for (int off = 32; off; off >>= 1) m = fmaxf(m, __shfl_down(m, off));
  if ((tid & 63) == 0) r1[tid >> 6] = m;
  __syncthreads();
  float mt = fmaxf(fmaxf(r1[0], r1[1]), fmaxf(r1[2], r1[3]));
  float e = __expf(v - mt);
  float s = e;
  for (int off = 32; off; off >>= 1) s += __shfl_down(s, off);
  if ((tid & 63) == 0) r2[tid >> 6] = s;
  __syncthreads();
  float st = r2[0] + r2[1] + r2[2] + r2[3];
  mv[tid] = e / st;
  __syncthreads();
  float g = 0.f; int p = 0;
  for (int i2 = 0; i2 < CC; ++i2)
    if (sidx[i2] == tid) { g += mv[i2]; p = 1; }
  gsc[tid] = g; pres[tid] = p;
  int pc = p;
  for (int off = 32; off; off >>= 1) pc += __shfl_down(pc, off);
  if ((tid & 63) == 0) r3[tid >> 6] = pc;
  __syncthreads();
  if (tid == 0) cnt[b] = r3[0] + r3[1] + r3[2] + r3[3];
  int c = 255 - tid;
  float val = pres[c] ? gsc[c] : -INFINITY;
  keys[tid] = ((unsigned long long)f2ord(val) << 32) | (unsigned)c;
  __syncthreads();
  for (int ksz = 2; ksz <= 256; ksz <<= 1) {
    for (int jj = ksz >> 1; jj > 0; jj >>= 1) {
      int ixj = tid ^ jj;
      if (ixj > tid) {
        unsigned long long a = keys[tid], o = keys[ixj];
        bool descBlock = ((tid & ksz) == 0);
        bool sw = descBlock ? (a < o) : (a > o);
        if (sw) { keys[tid] = o; keys[ixj] = a; }
      }
      __syncthreads();
    }
  }
  unsigned long long kk = keys[tid];
  int cc2 = (int)(kk & 0xFFFFFFFFull);
  float vv = pres[cc2] ? gsc[cc2] : -INFINITY;
  sscore[b * CC + tid] = vv;
  svals[b * CC + tid] = cc2;
}

// ---------------- Kernel F: fused weights + mask + output (round-18 structure) ----------------
__global__ __launch_bounds__(256) void k_maskout(const float* __restrict__ fp,
                                                 const float* __restrict__ ssc,
                                                 const int* __restrict__ svals,
                                                 const int* __restrict__ cnt,
                                                 float* __restrict__ out) {
  const int b = blockIdx.y;
  const int tid = threadIdx.x;
  const int pos = tid & 31;                  // 0..31
  const int kq = tid >> 5;                   // 0..7
  const int hw4 = blockIdx.x * 32 + pos;     // float4 index < 2304
  __shared__ int cshare[16];
  __shared__ float sh1[2], sh2[2];
  __shared__ int minks;
  __shared__ float wls[128];
  if (tid < 16) cshare[tid] = cnt[tid];
  __syncthreads();
  if (tid == 0) {
    int mn = 0x7fffffff;
#pragma unroll
    for (int t = 0; t < CB; ++t) mn = min(mn, cshare[t]);
    minks = (mn + 1) >> 1;
  }
  __syncthreads();
  const int mink = minks;
  // inline k_wsel (same reduce structure -> bitwise-identical weights)
  float ew = 0.f;
  if (tid < 128) {
    float v = (tid < mink) ? ssc[b * CC + tid] : -INFINITY;
    float m = v;
    for (int off = 32; off; off >>= 1) m = fmaxf(m, __shfl_down(m, off));
    if ((tid & 63) == 0) sh1[tid >> 6] = m;
  }
  __syncthreads();
  if (tid < 128) {
    float v = (tid < mink) ? ssc[b * CC + tid] : -INFINITY;
    float mt = fmaxf(sh1[0], sh1[1]);
    ew = (tid < mink) ? __expf(v - mt) : 0.f;
    float s = ew;
    for (int off = 32; off; off >>= 1) s += __shfl_down(s, off);
    if ((tid & 63) == 0) sh2[tid >> 6] = s;
  }
  __syncthreads();
  if (tid < 128) {
    float st = sh2[0] + sh2[1];
    wls[tid] = ew / st;
  }
  __syncthreads();
  const float* base = fp + (size_t)b * CC * PHW;
  const int qlo = (mink * kq) >> 3, qhi = (mink * (kq + 1)) >> 3;
  float4 acc = make_float4(0.f, 0.f, 0.f, 0.f);
  int k = qlo;
  for (; k + 4 <= qhi; k += 4) {
    float4 vv[4]; float wk[4];
#pragma unroll
    for (int t = 0; t < 4; ++t) {
      int c = svals[b * CC + k + t];
      wk[t] = wls[k + t];
      vv[t] = ((const float4*)(base + (size_t)c * PHW))[hw4];
    }
#pragma unroll
    for (int t = 0; t < 4; ++t) {
      acc.x += wk[t] * sigmoidf_(vv[t].x);
      acc.y += wk[t] * sigmoidf_(vv[t].y);
      acc.z += wk[t] * sigmoidf_(vv[t].z);
      acc.w += wk[t] * sigmoidf_(vv[t].w);
    }
  }
  for (; k < qhi; ++k) {
    int c = svals[b * CC + k];
    float wk = wls[k];
    float4 v = ((const float4*)(base + (size_t)c * PHW))[hw4];
    acc.x += wk * sigmoidf_(v.x);
    acc.y += wk * sigmoidf_(v.y);
    acc.z += wk * sigmoidf_(v.z);
    acc.w += wk * sigmoidf_(v.w);
  }
  __shared__ __align__(16) float4 sh[8][32];
  __shared__ __align__(16) float4 msh[32];
  sh[kq][pos] = acc;
  __syncthreads();
  if (kq == 0) {
    float4 r = sh[0][pos];
#pragma unroll
    for (int t = 1; t < 8; ++t) {
      float4 a = sh[t][pos];
      r.x += a.x; r.y += a.y; r.z += a.z; r.w += a.w;
    }
    msh[pos] = r;
  }
  __syncthreads();
  const float4 mk = msh[pos];
  float* outb = out + (size_t)b * CC * PHW;
#pragma unroll
  for (int grp = 0; grp < 4; ++grp) {
    float4 v[8];
#pragma unroll
    for (int j = 0; j < 8; ++j) {
      const int c = (grp * 8 + j) * 8 + kq;
      v[j] = ((const float4*)(base + (size_t)c * PHW))[hw4];
    }
#pragma unroll
    for (int j = 0; j < 8; ++j) {
      const int c = (grp * 8 + j) * 8 + kq;
      float4 o;
      o.x = v[j].x * (1.f + mk.x);
      o.y = v[j].y * (1.f + mk.y);
      o.z = v[j].z * (1.f + mk.z);
      o.w = v[j].w * (1.f + mk.w);
      ((float4*)(outb + (size_t)c * PHW))[hw4] = o;
    }
  }
}

extern "C" void kernel_launch(void* const* d_in, const int* in_sizes, int n_in,
                              void* d_out, int out_size, void* d_ws, size_t ws_size,
                              hipStream_t stream) {
  (void)in_sizes; (void)n_in; (void)out_size;
  const float* fp = (const float*)d_in[0];
  const float* fms = (const float*)d_in[1];
  float* out = (float*)d_out;

  // Big scratch in d_out (dead before k_maskout overwrites it):
  //   padjP: 16*256*3*2304 ushorts = 14,155,776 float-slots
  //   msP  : same, at float-offset 14,155,776
  //   dot  : 16*256*256 floats at float-offset 28,311,552  (ends 29.36M < 37.75M)
  unsigned short* padjP = (unsigned short*)out;
  unsigned short* msP = (unsigned short*)(out + (size_t)14155776);
  float* dotp = out + (size_t)28311552;

  if (ws_size < (size_t)183000 * 4) return;
  float* wsf = (float*)d_ws;
  float* meanp = wsf;               // 4096
  float* pnv = wsf + 4096;          // 4096
  float* meanms = wsf + 8192;       // 4096
  float* msn = wsf + 12288;         // 4096
  float* ssc = wsf + 20480;         // 4096
  int* sv = (int*)(wsf + 178176);   // 4096
  int* cntp = (int*)(wsf + 182272); // 16

  k_stats<<<8192, 256, 0, stream>>>(fp, fms, padjP, msP, meanp, pnv, meanms, msn);
  k_gemm<<<256, 256, 0, stream>>>(msP, padjP, dotp);
  k_select<<<CB, 256, 0, stream>>>(dotp, meanp, pnv, meanms, msn, ssc, sv, cntp);
  k_maskout<<<dim3(PHW / 4 / 32, CB), 256, 0, stream>>>(fp, ssc, sv, cntp, out);
}

// Round 21
// 211.660 us; speedup vs baseline: 1.0177x; 1.0177x over previous
//
#include <hip/hip_runtime.h>
#include <hip/hip_bf16.h>
#include <math.h>
#include <float.h>

// Problem constants
constexpr int CB = 16;        // batch
constexpr int CC = 256;       // channels
constexpr int PH = 96, PW = 96, PHW = 9216;
constexpr int MH = 48, MW = 48, MHW = 2304;
constexpr int GSTEPS = MHW / 32;   // 72 mfma k-steps
constexpr int TPAD = 100;     // padded tmp row stride

typedef __bf16 bf16x8 __attribute__((ext_vector_type(8)));
typedef float f32x4 __attribute__((ext_vector_type(4)));
typedef unsigned short ushort8 __attribute__((ext_vector_type(8)));

__device__ __forceinline__ float sigmoidf_(float x) { return 1.f / (1.f + __expf(-x)); }

__device__ __forceinline__ unsigned f2ord(float f) {
  unsigned u = __float_as_uint(f);
  return (u & 0x80000000u) ? ~u : (u | 0x80000000u);
}

// Truncation-based 3-term bf16 split: v = b1 + b2 + b3 + err, |err| <= 2^-24 |v|.
__device__ __forceinline__ void split3(float v, unsigned short& h1, unsigned short& h2,
                                       unsigned short& h3) {
  unsigned u1 = __float_as_uint(v) & 0xFFFF0000u;
  float r1 = v - __uint_as_float(u1);
  unsigned u2 = __float_as_uint(r1) & 0xFFFF0000u;
  float r2 = r1 - __uint_as_float(u2);
  h1 = (unsigned short)(u1 >> 16);
  h2 = (unsigned short)(u2 >> 16);
  h3 = (unsigned short)(__float_as_uint(r2) >> 16);
}

// ---------------- Kernel A+B merged: stats + bf16 planes for both inputs
// fp path: explicit 2-buffer 5-task schedule -> 8 float4 outstanding at VGPR ~48
// (below the 64-VGPR/8-wave cliff). Compute order ascending -> bitwise identical.
__global__ __launch_bounds__(256) void k_stats(const float* __restrict__ fp,
                                               const float* __restrict__ fms,
                                               unsigned short* __restrict__ padjP,
                                               unsigned short* __restrict__ msP,
                                               float* __restrict__ meanp,
                                               float* __restrict__ pn,
                                               float* __restrict__ meanms,
                                               float* __restrict__ msn) {
  __shared__ __align__(16) float smem[MH * TPAD];   // 19.2 KB (aliased by both paths)
  __shared__ float rs[4], rss[4];
  const int tid = threadIdx.x;
  if (blockIdx.x < 4096) {
    // ---- f_p path ----
    const int bc = blockIdx.x;
    float (*tmp)[TPAD] = (float(*)[TPAD])smem;
    const float* img = fp + (size_t)bc * PHW;
    const int NT4 = MH * (PW / 4);   // 1152
    float s = 0.f, ss = 0.f;

    auto task_load = [&](int idx4, float4* r4) {
      const int u = idx4 / (PW / 4), w4 = (idx4 - u * (PW / 4)) * 4;
      int r0, r1, r2, r3;
      if (u == 0) { r0 = 0; r1 = 1; r2 = 2; r3 = 2; }
      else if (u == MH - 1) { r0 = PH - 3; r1 = PH - 2; r2 = PH - 1; r3 = PH - 1; }
      else { r0 = 2 * u - 1; r1 = 2 * u; r2 = 2 * u + 1; r3 = 2 * u + 2; }
      r4[0] = *(const float4*)&img[r0 * PW + w4];
      r4[1] = *(const float4*)&img[r1 * PW + w4];
      r4[2] = *(const float4*)&img[r2 * PW + w4];
      r4[3] = *(const float4*)&img[r3 * PW + w4];
    };
    auto task_compute = [&](int idx4, const float4* r4) {
      const int u = idx4 / (PW / 4), w4 = (idx4 - u * (PW / 4)) * 4;
      const float4 a = r4[0], b = r4[1], c = r4[2], d = r4[3];
      float4 v, p0, p1;
      if (u == 0) {
        v.x = a.x + 0.75f * b.x + 0.25f * c.x;
        v.y = a.y + 0.75f * b.y + 0.25f * c.y;
        v.z = a.z + 0.75f * b.z + 0.25f * c.z;
        v.w = a.w + 0.75f * b.w + 0.25f * c.w;
        p0 = a; p1 = b;
      } else if (u == MH - 1) {
        v.x = 0.25f * a.x + 0.75f * b.x + c.x;
        v.y = 0.25f * a.y + 0.75f * b.y + c.y;
        v.z = 0.25f * a.z + 0.75f * b.z + c.z;
        v.w = 0.25f * a.w + 0.75f * b.w + c.w;
        p0 = b; p1 = c;
      } else {
        v.x = 0.25f * (a.x + d.x) + 0.75f * (b.x + c.x);
        v.y = 0.25f * (a.y + d.y) + 0.75f * (b.y + c.y);
        v.z = 0.25f * (a.z + d.z) + 0.75f * (b.z + c.z);
        v.w = 0.25f * (a.w + d.w) + 0.75f * (b.w + c.w);
        p0 = b; p1 = c;
      }
      s += (p0.x + p0.y + p0.z + p0.w) + (p1.x + p1.y + p1.z + p1.w);
      ss += (p0.x * p0.x + p0.y * p0.y + p0.z * p0.z + p0.w * p0.w) +
            (p1.x * p1.x + p1.y * p1.y + p1.z * p1.z + p1.w * p1.w);
      *(float4*)&tmp[u][w4] = v;
    };

    // Tasks: tid, tid+256, tid+512, tid+768 (all < 1152), tid+1024 (guarded).
    {
      float4 bufA[4], bufB[4];
      const bool t4 = (tid + 1024) < NT4;
      task_load(tid, bufA);
      task_load(tid + 256, bufB);
      task_compute(tid, bufA);
      task_load(tid + 512, bufA);
      task_compute(tid + 256, bufB);
      task_load(tid + 768, bufB);
      task_compute(tid + 512, bufA);
      if (t4) task_load(tid + 1024, bufA);
      task_compute(tid + 768, bufB);
      if (t4) task_compute(tid + 1024, bufA);
    }
    for (int off = 32; off; off >>= 1) { s += __shfl_down(s, off); ss += __shfl_down(ss, off); }
    if ((tid & 63) == 0) { rs[tid >> 6] = s; rss[tid >> 6] = ss; }
    __syncthreads();
    if (tid == 0) {
      float S = rs[0] + rs[1] + rs[2] + rs[3];
      float SS = rss[0] + rss[1] + rss[2] + rss[3];
      meanp[bc] = S / (float)PHW;
      pn[bc] = sqrtf(fmaxf(SS - S * S / (float)PHW, 0.f));
    }
    // Phase 3: col adjoint + split3, 8 outputs per task, ushort8 stores.
    unsigned short* outp = padjP + (size_t)bc * 3 * MHW;   // [c][plane][k]
    for (int idx = tid; idx < MH * 6; idx += 256) {        // 288 tasks
      const int u = idx / 6, q = idx - u * 6;
      const int v0 = 8 * q;
      const float* r = tmp[u];
      float val[8];
#pragma unroll
      for (int t = 0; t < 8; ++t) {
        const int v = v0 + t;
        if (v == 0)
          val[t] = r[0] + 0.75f * r[1] + 0.25f * r[2];
        else if (v == MW - 1)
          val[t] = 0.25f * r[PW - 3] + 0.75f * r[PW - 2] + r[PW - 1];
        else
          val[t] = 0.25f * (r[2 * v - 1] + r[2 * v + 2]) + 0.75f * (r[2 * v] + r[2 * v + 1]);
      }
      ushort8 h1, h2, h3;
#pragma unroll
      for (int t = 0; t < 8; ++t)
        split3(val[t], ((unsigned short*)&h1)[t], ((unsigned short*)&h2)[t],
               ((unsigned short*)&h3)[t]);
      const int k0 = u * MW + v0;
      *(ushort8*)&outp[k0] = h1;
      *(ushort8*)&outp[MHW + k0] = h2;
      *(ushort8*)&outp[2 * MHW + k0] = h3;
    }
  } else {
    // ---- f_ms path ----
    const int bc = blockIdx.x - 4096;
    float* m = smem;            // 2304 floats
    float* t = smem + MHW;      // 2304 floats (fits: 48*100 = 4800 >= 4608)
    const float* img = fms + (size_t)bc * MHW;
    float s = 0.f;
    for (int q = tid; q < MHW / 4; q += 256) {
      float4 v = ((const float4*)img)[q];
      ((float4*)m)[q] = v;
      s += v.x + v.y + v.z + v.w;
    }
    for (int off = 32; off; off >>= 1) s += __shfl_down(s, off);
    if ((tid & 63) == 0) rs[tid >> 6] = s;
    __syncthreads();
    const float mean = (rs[0] + rs[1] + rs[2] + rs[3]) / (float)MHW;
    for (int idx = tid; idx < MHW; idx += 256) {
      const int i = idx / MW, j = idx - i * MW;
      const float c = m[idx];
      const float l = (j > 0) ? m[idx - 1] : 0.f;
      const float r = (j < MW - 1) ? m[idx + 1] : 0.f;
      const float dj = (j == 0 || j == MW - 1) ? 1.625f : 1.25f;
      t[idx] = dj * c + 0.375f * (l + r);
    }
    __syncthreads();
    float ss = 0.f;
    for (int idx = tid; idx < MHW; idx += 256) {
      const int i = idx / MW;
      const float c = t[idx];
      const float up = (i > 0) ? t[idx - MW] : 0.f;
      const float dn = (i < MH - 1) ? t[idx + MW] : 0.f;
      const float di = (i == 0 || i == MH - 1) ? 1.625f : 1.25f;
      ss += m[idx] * (di * c + 0.375f * (up + dn));
    }
    for (int off = 32; off; off >>= 1) ss += __shfl_down(ss, off);
    if ((tid & 63) == 0) rss[tid >> 6] = ss;
    __syncthreads();
    if (tid == 0) {
      float SS = rss[0] + rss[1] + rss[2] + rss[3];
      meanms[bc] = mean;
      msn[bc] = sqrtf(fmaxf(SS - (float)PHW * mean * mean, 0.f));
    }
    unsigned short* outp = msP + (size_t)bc * 3 * MHW;   // [c][plane][k]
    for (int i8 = tid; i8 < MHW / 8; i8 += 256) {        // 288 tasks
      const int i = 8 * i8;
      float4 va = *(const float4*)&m[i];
      float4 vb = *(const float4*)&m[i + 4];
      ushort8 h1, h2, h3;
      split3(va.x, ((unsigned short*)&h1)[0], ((unsigned short*)&h2)[0], ((unsigned short*)&h3)[0]);
      split3(va.y, ((unsigned short*)&h1)[1], ((unsigned short*)&h2)[1], ((unsigned short*)&h3)[1]);
      split3(va.z, ((unsigned short*)&h1)[2], ((unsigned short*)&h2)[2], ((unsigned short*)&h3)[2]);
      split3(va.w, ((unsigned short*)&h1)[3], ((unsigned short*)&h2)[3], ((unsigned short*)&h3)[3]);
      split3(vb.x, ((unsigned short*)&h1)[4], ((unsigned short*)&h2)[4], ((unsigned short*)&h3)[4]);
      split3(vb.y, ((unsigned short*)&h1)[5], ((unsigned short*)&h2)[5], ((unsigned short*)&h3)[5]);
      split3(vb.z, ((unsigned short*)&h1)[6], ((unsigned short*)&h2)[6], ((unsigned short*)&h3)[6]);
      split3(vb.w, ((unsigned short*)&h1)[7], ((unsigned short*)&h2)[7], ((unsigned short*)&h3)[7]);
      *(ushort8*)&outp[i] = h1;
      *(ushort8*)&outp[MHW + i] = h2;
      *(ushort8*)&outp[2 * MHW + i] = h3;
    }
  }
}

// ---------------- Kernel C: split-bf16 MFMA GEMM, double-buffered (1 barrier/step) ----------------
__global__ __launch_bounds__(256) void k_gemm(const unsigned short* __restrict__ msP,
                                              const unsigned short* __restrict__ padjP,
                                              float* __restrict__ dotp) {
  __shared__ unsigned short As[2][2][3][64][40];   // [buf][mat][plane][row][k] = 122880 B
  const int n = blockIdx.x;                     // 0..255
  const int xcd = n & 7, slot = n >> 3;
  const int b = xcd * 2 + (slot >> 4);          // 2 batches per XCD
  const int xy = slot & 15;
  const int i0 = (xy >> 2) * 64, j0 = (xy & 3) * 64;
  const int tid = threadIdx.x, lane = tid & 63, wid = tid >> 6;
  const int wr = wid >> 1, wc = wid & 1;        // wave quadrant
  const int fr = lane & 15, fq = lane >> 4;

  const unsigned short* mats[2] = {
    msP + (size_t)(b * CC + i0) * 3 * MHW,
    padjP + (size_t)(b * CC + j0) * 3 * MHW
  };
  const unsigned short* gsrc[6];
  int lmat[6], lpl[6], lrow[6], lch[6];
#pragma unroll
  for (int q = 0; q < 6; ++q) {
    int t = tid + q * 256;                      // 1536 tasks: 128 rows x 3 planes x 4 chunks
    int ch = t & 3, pl = (t >> 2) % 3, r128 = t / 12;
    int mat = r128 >> 6, row = r128 & 63;
    gsrc[q] = mats[mat] + ((size_t)row * 3 + pl) * MHW + ch * 8;
    lmat[q] = mat; lpl[q] = pl; lrow[q] = row; lch[q] = ch;
  }
  bf16x8 stg[6];
  f32x4 acc[2][2] = {};

  auto g_load = [&](int kt) {
#pragma unroll
    for (int q = 0; q < 6; ++q) stg[q] = *(const bf16x8*)(gsrc[q] + kt);
  };
  auto l_store = [&](int buf) {
#pragma unroll
    for (int q = 0; q < 6; ++q)
      *(bf16x8*)&As[buf][lmat[q]][lpl[q]][lrow[q]][lch[q] * 8] = stg[q];
  };

  g_load(0);
  l_store(0);
  if (GSTEPS > 1) g_load(32);
  __syncthreads();
  int cur = 0;
  for (int step = 0; step < GSTEPS; ++step) {
    if (step + 1 < GSTEPS) l_store(cur ^ 1);     // store prefetched step+1 into idle buffer
    if (step + 2 < GSTEPS) g_load((step + 2) * 32);
    bf16x8 af[2][3], bfr[2][3];
#pragma unroll
    for (int ti = 0; ti < 2; ++ti)
#pragma unroll
      for (int p = 0; p < 3; ++p) {
        af[ti][p] = *(const bf16x8*)&As[cur][0][p][wr * 32 + ti * 16 + fr][fq * 8];
        bfr[ti][p] = *(const bf16x8*)&As[cur][1][p][wc * 32 + ti * 16 + fr][fq * 8];
      }
#pragma unroll
    for (int ti = 0; ti < 2; ++ti)
#pragma unroll
      for (int tj = 0; tj < 2; ++tj) {
        f32x4 c = acc[ti][tj];
        c = __builtin_amdgcn_mfma_f32_16x16x32_bf16(af[ti][0], bfr[tj][0], c, 0, 0, 0);
        c = __builtin_amdgcn_mfma_f32_16x16x32_bf16(af[ti][0], bfr[tj][1], c, 0, 0, 0);
        c = __builtin_amdgcn_mfma_f32_16x16x32_bf16(af[ti][1], bfr[tj][0], c, 0, 0, 0);
        c = __builtin_amdgcn_mfma_f32_16x16x32_bf16(af[ti][0], bfr[tj][2], c, 0, 0, 0);
        c = __builtin_amdgcn_mfma_f32_16x16x32_bf16(af[ti][1], bfr[tj][1], c, 0, 0, 0);
        c = __builtin_amdgcn_mfma_f32_16x16x32_bf16(af[ti][2], bfr[tj][0], c, 0, 0, 0);
        acc[ti][tj] = c;
      }
    __syncthreads();   // waves done reading As[cur]; stores to As[cur^1] visible
    cur ^= 1;
  }
  // Epilogue: C/D layout col = lane&15, row = (lane>>4)*4 + reg  [m89-verified]
  float* drow = dotp + ((size_t)b * CC + i0) * CC + j0;
#pragma unroll
  for (int ti = 0; ti < 2; ++ti)
#pragma unroll
    for (int tj = 0; tj < 2; ++tj)
#pragma unroll
      for (int j = 0; j < 4; ++j) {
        int row = wr * 32 + ti * 16 + fq * 4 + j;
        int col = wc * 32 + tj * 16 + fr;
        drow[(size_t)row * CC + col] = acc[ti][tj][j];
      }
}

// ---------------- Kernel D: merged rowmax + group select + bitonic sort (per batch) ----------------
__global__ __launch_bounds__(256) void k_select(const float* __restrict__ dotp,
                                                const float* __restrict__ meanp,
                                                const float* __restrict__ pn,
                                                const float* __restrict__ meanms,
                                                const float* __restrict__ msn,
                                                float* __restrict__ sscore,
                                                int* __restrict__ svals,
                                                int* __restrict__ cnt) {
  const int b = blockIdx.x, tid = threadIdx.x;
  __shared__ float mv[CC];
  __shared__ int sidx[CC];
  __shared__ float gsc[CC];
  __shared__ int pres[CC];
  __shared__ unsigned long long keys[CC];
  __shared__ float r1[4], r2[4];
  __shared__ int r3[4];
  __shared__ __align__(16) float mps[CC], pns[CC];
  mps[tid] = meanp[b * CC + tid];
  pns[tid] = pn[b * CC + tid];
  __syncthreads();
  const int r = b * CC + tid;
  const float* d0 = dotp + (size_t)r * CC;
  const float mm = meanms[r];
  const float inv = 100.f / msn[r];
  float best = -INFINITY; int bj = 0;
  for (int blk = 0; blk < 8; ++blk) {
    float4 v[8];
#pragma unroll
    for (int t = 0; t < 8; ++t) v[t] = ((const float4*)d0)[blk * 8 + t];
#pragma unroll
    for (int t = 0; t < 8; ++t) {
      const int j4 = blk * 8 + t;
      float4 mp4 = ((const float4*)mps)[j4];
      float4 pn4 = ((const float4*)pns)[j4];
      float sv[4];
      sv[0] = (v[t].x - (float)PHW * mm * mp4.x) * inv / pn4.x;
      sv[1] = (v[t].y - (float)PHW * mm * mp4.y) * inv / pn4.y;
      sv[2] = (v[t].z - (float)PHW * mm * mp4.z) * inv / pn4.z;
      sv[3] = (v[t].w - (float)PHW * mm * mp4.w) * inv / pn4.w;
#pragma unroll
      for (int q = 0; q < 4; ++q)
        if (sv[q] > best) { best = sv[q]; bj = j4 * 4 + q; }
    }
  }
  const float v = best;
  sidx[tid] = bj;
  // ---- group logic (verbatim) ----
  float m = v;
  for (int off = 32; off; off >>= 1) m = fmaxf(m, __shfl_down(m, off));
  if ((tid & 63) == 0) r1[tid >> 6] = m;
  __syncthreads();
  float mt = fmaxf(fmaxf(r1[0], r1[1]), fmaxf(r1[2], r1[3]));
  float e = __expf(v - mt);
  float s = e;
  for (int off = 32; off; off >>= 1) s += __shfl_down(s, off);
  if ((tid & 63) == 0) r2[tid >> 6] = s;
  __syncthreads();
  float st = r2[0] + r2[1] + r2[2] + r2[3];
  mv[tid] = e / st;
  __syncthreads();
  float g = 0.f; int p = 0;
  for (int i2 = 0; i2 < CC; ++i2)
    if (sidx[i2] == tid) { g += mv[i2]; p = 1; }
  gsc[tid] = g; pres[tid] = p;
  int pc = p;
  for (int off = 32; off; off >>= 1) pc += __shfl_down(pc, off);
  if ((tid & 63) == 0) r3[tid >> 6] = pc;
  __syncthreads();
  if (tid == 0) cnt[b] = r3[0] + r3[1] + r3[2] + r3[3];
  int c = 255 - tid;
  float val = pres[c] ? gsc[c] : -INFINITY;
  keys[tid] = ((unsigned long long)f2ord(val) << 32) | (unsigned)c;
  __syncthreads();
  for (int ksz = 2; ksz <= 256; ksz <<= 1) {
    for (int jj = ksz >> 1; jj > 0; jj >>= 1) {
      int ixj = tid ^ jj;
      if (ixj > tid) {
        unsigned long long a = keys[tid], o = keys[ixj];
        bool descBlock = ((tid & ksz) == 0);
        bool sw = descBlock ? (a < o) : (a > o);
        if (sw) { keys[tid] = o; keys[ixj] = a; }
      }
      __syncthreads();
    }
  }
  unsigned long long kk = keys[tid];
  int cc2 = (int)(kk & 0xFFFFFFFFull);
  float vv = pres[cc2] ? gsc[cc2] : -INFINITY;
  sscore[b * CC + tid] = vv;
  svals[b * CC + tid] = cc2;
}

// ---------------- Kernel F: fused weights + mask + output (round-18 structure) ----------------
__global__ __launch_bounds__(256) void k_maskout(const float* __restrict__ fp,
                                                 const float* __restrict__ ssc,
                                                 const int* __restrict__ svals,
                                                 const int* __restrict__ cnt,
                                                 float* __restrict__ out) {
  const int b = blockIdx.y;
  const int tid = threadIdx.x;
  const int pos = tid & 31;                  // 0..31
  const int kq = tid >> 5;                   // 0..7
  const int hw4 = blockIdx.x * 32 + pos;     // float4 index < 2304
  __shared__ int cshare[16];
  __shared__ float sh1[2], sh2[2];
  __shared__ int minks;
  __shared__ float wls[128];
  if (tid < 16) cshare[tid] = cnt[tid];
  __syncthreads();
  if (tid == 0) {
    int mn = 0x7fffffff;
#pragma unroll
    for (int t = 0; t < CB; ++t) mn = min(mn, cshare[t]);
    minks = (mn + 1) >> 1;
  }
  __syncthreads();
  const int mink = minks;
  // inline k_wsel (same reduce structure -> bitwise-identical weights)
  float ew = 0.f;
  if (tid < 128) {
    float v = (tid < mink) ? ssc[b * CC + tid] : -INFINITY;
    float m = v;
    for (int off = 32; off; off >>= 1) m = fmaxf(m, __shfl_down(m, off));
    if ((tid & 63) == 0) sh1[tid >> 6] = m;
  }
  __syncthreads();
  if (tid < 128) {
    float v = (tid < mink) ? ssc[b * CC + tid] : -INFINITY;
    float mt = fmaxf(sh1[0], sh1[1]);
    ew = (tid < mink) ? __expf(v - mt) : 0.f;
    float s = ew;
    for (int off = 32; off; off >>= 1) s += __shfl_down(s, off);
    if ((tid & 63) == 0) sh2[tid >> 6] = s;
  }
  __syncthreads();
  if (tid < 128) {
    float st = sh2[0] + sh2[1];
    wls[tid] = ew / st;
  }
  __syncthreads();
  const float* base = fp + (size_t)b * CC * PHW;
  const int qlo = (mink * kq) >> 3, qhi = (mink * (kq + 1)) >> 3;
  float4 acc = make_float4(0.f, 0.f, 0.f, 0.f);
  int k = qlo;
  for (; k + 4 <= qhi; k += 4) {
    float4 vv[4]; float wk[4];
#pragma unroll
    for (int t = 0; t < 4; ++t) {
      int c = svals[b * CC + k + t];
      wk[t] = wls[k + t];
      vv[t] = ((const float4*)(base + (size_t)c * PHW))[hw4];
    }
#pragma unroll
    for (int t = 0; t < 4; ++t) {
      acc.x += wk[t] * sigmoidf_(vv[t].x);
      acc.y += wk[t] * sigmoidf_(vv[t].y);
      acc.z += wk[t] * sigmoidf_(vv[t].z);
      acc.w += wk[t] * sigmoidf_(vv[t].w);
    }
  }
  for (; k < qhi; ++k) {
    int c = svals[b * CC + k];
    float wk = wls[k];
    float4 v = ((const float4*)(base + (size_t)c * PHW))[hw4];
    acc.x += wk * sigmoidf_(v.x);
    acc.y += wk * sigmoidf_(v.y);
    acc.z += wk * sigmoidf_(v.z);
    acc.w += wk * sigmoidf_(v.w);
  }
  __shared__ __align__(16) float4 sh[8][32];
  __shared__ __align__(16) float4 msh[32];
  sh[kq][pos] = acc;
  __syncthreads();
  if (kq == 0) {
    float4 r = sh[0][pos];
#pragma unroll
    for (int t = 1; t < 8; ++t) {
      float4 a = sh[t][pos];
      r.x += a.x; r.y += a.y; r.z += a.z; r.w += a.w;
    }
    msh[pos] = r;
  }
  __syncthreads();
  const float4 mk = msh[pos];
  float* outb = out + (size_t)b * CC * PHW;
#pragma unroll
  for (int grp = 0; grp < 4; ++grp) {
    float4 v[8];
#pragma unroll
    for (int j = 0; j < 8; ++j) {
      const int c = (grp * 8 + j) * 8 + kq;
      v[j] = ((const float4*)(base + (size_t)c * PHW))[hw4];
    }
#pragma unroll
    for (int j = 0; j < 8; ++j) {
      const int c = (grp * 8 + j) * 8 + kq;
      float4 o;
      o.x = v[j].x * (1.f + mk.x);
      o.y = v[j].y * (1.f + mk.y);
      o.z = v[j].z * (1.f + mk.z);
      o.w = v[j].w * (1.f + mk.w);
      ((float4*)(outb + (size_t)c * PHW))[hw4] = o;
    }
  }
}

extern "C" void kernel_launch(void* const* d_in, const int* in_sizes, int n_in,
                              void* d_out, int out_size, void* d_ws, size_t ws_size,
                              hipStream_t stream) {
  (void)in_sizes; (void)n_in; (void)out_size;
  const float* fp = (const float*)d_in[0];
  const float* fms = (const float*)d_in[1];
  float* out = (float*)d_out;

  // Big scratch in d_out (dead before k_maskout overwrites it):
  //   padjP: 16*256*3*2304 ushorts = 14,155,776 float-slots
  //   msP  : same, at float-offset 14,155,776
  //   dot  : 16*256*256 floats at float-offset 28,311,552  (ends 29.36M < 37.75M)
  unsigned short* padjP = (unsigned short*)out;
  unsigned short* msP = (unsigned short*)(out + (size_t)14155776);
  float* dotp = out + (size_t)28311552;

  if (ws_size < (size_t)183000 * 4) return;
  float* wsf = (float*)d_ws;
  float* meanp = wsf;               // 4096
  float* pnv = wsf + 4096;          // 4096
  float* meanms = wsf + 8192;       // 4096
  float* msn = wsf + 12288;         // 4096
  float* ssc = wsf + 20480;         // 4096
  int* sv = (int*)(wsf + 178176);   // 4096
  int* cntp = (int*)(wsf + 182272); // 16

  k_stats<<<8192, 256, 0, stream>>>(fp, fms, padjP, msP, meanp, pnv, meanms, msn);
  k_gemm<<<256, 256, 0, stream>>>(msP, padjP, dotp);
  k_select<<<CB, 256, 0, stream>>>(dotp, meanp, pnv, meanms, msn, ssc, sv, cntp);
  k_maskout<<<dim3(PHW / 4 / 32, CB), 256, 0, stream>>>(fp, ssc, sv, cntp, out);
}